// Round 3
// baseline (602.789 us; speedup 1.0000x reference)
//
#include <hip/hip_runtime.h>

// Problem: T=8, N=256, F=128. All inputs/outputs FLOAT32 (per reference).
// Decomposition: y[t,i,j,f] = A[t,i,f] + B[t,j,f],
//   A = x @ w[:, :F]^T, B = x @ w[:, F:]^T   (per branch).
// BN train-mode stats decompose onto A/B:
//   mean = (SA+SB)/(T*N),  E[y^2] = (QA+QB)/(T*N) + 2*sum_t SA_t.SB_t/(T*N^2)
//
// Measured context (R2, 572.6us): harness poison-fill (2GiB, ~343us @6.25TB/s)
// is inside the timed region; our kernels total ~230us, k_edge ~200us vs a
// ~86us write roofline (537MB). R3 theory: k_edge blocks spent ~half their
// lifetime in a non-storing prologue (denominator pass + 3 barriers).
// R3: new k_denom computes all 1/L1 into r[16][256][256] (4MB, L2-resident)
// once; k_edge becomes a pure stream (register s/c, 1KB r-row stage with
// diagonal pre-zeroed, ONE barrier, then load->fma->nt-store only).

#define TT 8
#define NN 256
#define FF 128
// rows = T*N = 2048; per-array ws region = 2048*128 = 262144 floats
// ws layout (floats):
//   A1:0  B1:262144  A2:524288  B2:786432
//   B1t:1048576  B2t:1310720          (each [8 t][128 f][256 j])
//   sums:1572864[4096] sumsq:1576960[4096] scale:1581056[256] bias:1581312[256]
//   r:1581568 [16][256][256]  (1/L1 per (t*2+br, i, j))

typedef float vf4 __attribute__((ext_vector_type(4)));

// ---------------------------------------------------------------------------
// Kernel 1: A1,B1,A2,B2 [2048 rows][128 f] (+ transposed B1t,B2t) from x, w.
// 256 blocks x 128 threads; block = 8 rows; thread = output channel f.
// ---------------------------------------------------------------------------
__global__ __launch_bounds__(128) void k_matmul(
    const float* __restrict__ x,    // [2048][128]
    const float* __restrict__ w1,   // [128][256]
    const float* __restrict__ w2,   // [128][256]
    float* __restrict__ ws)
{
    __shared__ float xs[8][FF];
    const int tid = threadIdx.x;
    const int row0 = blockIdx.x * 8;

    {
        const float4* xv = (const float4*)(x + row0 * FF);
        ((float4*)xs)[tid]       = xv[tid];
        ((float4*)xs)[tid + 128] = xv[tid + 128];
    }
    __syncthreads();

    const int f = tid;
    float acc0[8], acc1[8], acc2[8], acc3[8];
    #pragma unroll
    for (int r = 0; r < 8; ++r) { acc0[r]=0.f; acc1[r]=0.f; acc2[r]=0.f; acc3[r]=0.f; }

    const float4* w1v = (const float4*)w1;  // row f = 64 float4 (32 A-half, 32 B-half)
    const float4* w2v = (const float4*)w2;

    #pragma unroll 4
    for (int c4 = 0; c4 < 32; ++c4) {
        float4 qa1 = w1v[f * 64 + c4];
        float4 qb1 = w1v[f * 64 + 32 + c4];
        float4 qa2 = w2v[f * 64 + c4];
        float4 qb2 = w2v[f * 64 + 32 + c4];
        const int c = c4 * 4;
        #pragma unroll
        for (int r = 0; r < 8; ++r) {
            float x0 = xs[r][c], x1 = xs[r][c + 1], x2 = xs[r][c + 2], x3 = xs[r][c + 3];
            acc0[r] = fmaf(x0, qa1.x, fmaf(x1, qa1.y, fmaf(x2, qa1.z, fmaf(x3, qa1.w, acc0[r]))));
            acc1[r] = fmaf(x0, qb1.x, fmaf(x1, qb1.y, fmaf(x2, qb1.z, fmaf(x3, qb1.w, acc1[r]))));
            acc2[r] = fmaf(x0, qa2.x, fmaf(x1, qa2.y, fmaf(x2, qa2.z, fmaf(x3, qa2.w, acc2[r]))));
            acc3[r] = fmaf(x0, qb2.x, fmaf(x1, qb2.y, fmaf(x2, qb2.z, fmaf(x3, qb2.w, acc3[r]))));
        }
    }

    float* A1 = ws;
    float* B1 = ws + 262144;
    float* A2 = ws + 524288;
    float* B2 = ws + 786432;
    #pragma unroll
    for (int r = 0; r < 8; ++r) {
        int row = row0 + r;
        A1[row * FF + f] = acc0[r];
        B1[row * FF + f] = acc1[r];
        A2[row * FF + f] = acc2[r];
        B2[row * FF + f] = acc3[r];
    }

    // transposed B copies: thread f holds B[row0..row0+7][f] in acc1/acc3
    {
        const int t  = row0 >> 8;
        const int n0 = row0 & 255;
        float* b1t = ws + 1048576 + (t * FF + f) * NN + n0;
        float* b2t = ws + 1310720 + (t * FF + f) * NN + n0;
        vf4 p0 = {acc1[0], acc1[1], acc1[2], acc1[3]};
        vf4 p1 = {acc1[4], acc1[5], acc1[6], acc1[7]};
        vf4 q0 = {acc3[0], acc3[1], acc3[2], acc3[3]};
        vf4 q1 = {acc3[4], acc3[5], acc3[6], acc3[7]};
        *(vf4*)(b1t)     = p0;
        *(vf4*)(b1t + 4) = p1;
        *(vf4*)(b2t)     = q0;
        *(vf4*)(b2t + 4) = q1;
    }
}

// ---------------------------------------------------------------------------
// Kernel 2a: per-(array, t) channel sums and sum-of-squares over n.
// grid = 32 (t in [0,8) x arr in [0,4)), block = 256.
// ---------------------------------------------------------------------------
__global__ __launch_bounds__(256) void k_stats(
    const float* __restrict__ ab,
    float* __restrict__ sums, float* __restrict__ sumsq)
{
    const int bx = blockIdx.x;
    const int t = bx & 7, arr = bx >> 3;
    const float* A = ab + arr * 262144 + t * NN * FF;
    const int tid = threadIdx.x;
    const int f = tid & 127, h = tid >> 7;
    float s = 0.f, q = 0.f;
    for (int n = h; n < NN; n += 2) {
        float v = A[n * FF + f];
        s += v;
        q = fmaf(v, v, q);
    }
    __shared__ float ls[256], lq[256];
    ls[tid] = s; lq[tid] = q;
    __syncthreads();
    if (tid < 128) {
        sums [(arr * 8 + t) * FF + f] = ls[tid] + ls[tid + 128];
        sumsq[(arr * 8 + t) * FF + f] = lq[tid] + lq[tid + 128];
    }
}

// ---------------------------------------------------------------------------
// Kernel 2b: fold BN (train-mode, biased var) into per-channel scale/bias.
// 1 block x 256 threads (branch = tid>>7, f = tid&127).
// ---------------------------------------------------------------------------
__global__ __launch_bounds__(256) void k_scale(
    const float* __restrict__ sums, const float* __restrict__ sumsq,
    const float* __restrict__ g1, const float* __restrict__ b1,
    const float* __restrict__ g2, const float* __restrict__ b2,
    float* __restrict__ scale, float* __restrict__ bias)
{
    const int tid = threadIdx.x;
    const int br = tid >> 7, f = tid & 127;
    const int aA = 2 * br, aB = 2 * br + 1;
    float SA = 0.f, SB = 0.f, QA = 0.f, QB = 0.f, cross = 0.f;
    #pragma unroll
    for (int t = 0; t < TT; ++t) {
        float sa = sums[(aA * 8 + t) * FF + f];
        float sb = sums[(aB * 8 + t) * FF + f];
        SA += sa; SB += sb;
        cross = fmaf(sa, sb, cross);
        QA += sumsq[(aA * 8 + t) * FF + f];
        QB += sumsq[(aB * 8 + t) * FF + f];
    }
    const float invTN  = 1.0f / 2048.0f;    // 1/(T*N)
    const float invTNN = 1.0f / 262144.0f;  // 2/(T*N*N)
    float mA = SA * invTN, mB = SB * invTN;
    float m = mA + mB;
    float ey2 = (QA + QB) * invTN + cross * invTNN;
    float var = ey2 - m * m;
    float gf = br ? g2[f] : g1[f];
    float bf = br ? b2[f] : b1[f];
    float sc = gf * rsqrtf(var + 1e-5f);
    scale[br * FF + f] = sc;
    bias [br * FF + f] = bf - m * sc;
}

// ---------------------------------------------------------------------------
// Kernel 3: all L1 reciprocals r[t*2+br][i][j] = 1/max(l1, eps).
// grid = 256: block = ((t,br) in [0,16)) x (i-tile of 16). 256 threads:
// thread (jq = tid&63, ig = tid>>6) owns j-quad jq and i's ig*4..ig*4+3.
// Reads Bt coalesced (1KB/wave-instr); c_i[f] via uniform LDS broadcast.
// VALU-bound, ~5us device-wide.
// ---------------------------------------------------------------------------
__global__ __launch_bounds__(256) void k_denom(
    const float* __restrict__ ws,
    const float* __restrict__ scale, const float* __restrict__ bias,
    float* __restrict__ r)
{
    const int bx = blockIdx.x;
    const int tb = bx >> 4;              // t*2+br
    const int i0 = (bx & 15) * 16;
    const int br = tb & 1, t = tb >> 1;
    const int tid = threadIdx.x;

    const float* A  = ws + (2 * br) * 262144 + (t * NN + i0) * FF;  // 16 rows
    const float* Bt = ws + 1048576 + br * 262144 + t * FF * NN;     // [128][256]

    __shared__ float s_lds[FF];
    __shared__ float c_lds[16][FF];

    if (tid < FF) s_lds[tid] = scale[br * FF + tid];
    #pragma unroll
    for (int k = 0; k < 8; ++k) {
        int idx = k * 256 + tid;         // 0..2047 = 16 rows x 128 f
        int f = idx & 127;
        ((float*)c_lds)[idx] = fmaf(A[idx], scale[br * FF + f], bias[br * FF + f]);
    }
    __syncthreads();

    const int jq = tid & 63, ig = tid >> 6;
    vf4 z0 = {0,0,0,0}, z1 = z0, z2 = z0, z3 = z0;
    const float* bt = Bt + jq * 4;

    #pragma unroll 4
    for (int f = 0; f < FF; ++f) {
        vf4 b = *(const vf4*)(bt + f * NN);
        float sf = s_lds[f];
        vf4 d;
        d.x = b.x * sf; d.y = b.y * sf; d.z = b.z * sf; d.w = b.w * sf;
        float c0 = c_lds[ig * 4 + 0][f];
        float c1 = c_lds[ig * 4 + 1][f];
        float c2 = c_lds[ig * 4 + 2][f];
        float c3 = c_lds[ig * 4 + 3][f];
        z0.x += fmaxf(d.x + c0, 0.f); z0.y += fmaxf(d.y + c0, 0.f);
        z0.z += fmaxf(d.z + c0, 0.f); z0.w += fmaxf(d.w + c0, 0.f);
        z1.x += fmaxf(d.x + c1, 0.f); z1.y += fmaxf(d.y + c1, 0.f);
        z1.z += fmaxf(d.z + c1, 0.f); z1.w += fmaxf(d.w + c1, 0.f);
        z2.x += fmaxf(d.x + c2, 0.f); z2.y += fmaxf(d.y + c2, 0.f);
        z2.z += fmaxf(d.z + c2, 0.f); z2.w += fmaxf(d.w + c2, 0.f);
        z3.x += fmaxf(d.x + c3, 0.f); z3.y += fmaxf(d.y + c3, 0.f);
        z3.z += fmaxf(d.z + c3, 0.f); z3.w += fmaxf(d.w + c3, 0.f);
    }

    float* rb = r + ((size_t)tb * NN + (i0 + ig * 4)) * NN + jq * 4;
    vf4 o;
    o.x = 1.0f / fmaxf(z0.x, 1e-12f); o.y = 1.0f / fmaxf(z0.y, 1e-12f);
    o.z = 1.0f / fmaxf(z0.z, 1e-12f); o.w = 1.0f / fmaxf(z0.w, 1e-12f);
    *(vf4*)(rb + 0 * NN) = o;
    o.x = 1.0f / fmaxf(z1.x, 1e-12f); o.y = 1.0f / fmaxf(z1.y, 1e-12f);
    o.z = 1.0f / fmaxf(z1.z, 1e-12f); o.w = 1.0f / fmaxf(z1.w, 1e-12f);
    *(vf4*)(rb + 1 * NN) = o;
    o.x = 1.0f / fmaxf(z2.x, 1e-12f); o.y = 1.0f / fmaxf(z2.y, 1e-12f);
    o.z = 1.0f / fmaxf(z2.z, 1e-12f); o.w = 1.0f / fmaxf(z2.w, 1e-12f);
    *(vf4*)(rb + 2 * NN) = o;
    o.x = 1.0f / fmaxf(z3.x, 1e-12f); o.y = 1.0f / fmaxf(z3.y, 1e-12f);
    o.z = 1.0f / fmaxf(z3.z, 1e-12f); o.w = 1.0f / fmaxf(z3.w, 1e-12f);
    *(vf4*)(rb + 3 * NN) = o;
}

// ---------------------------------------------------------------------------
// Kernel 4: pure streaming kernel. One block per (t,br,i): 256 threads.
// Register s/c per lane; r-row staged to LDS (1KB, diagonal pre-zeroed by
// the staging thread -> no per-iter compare); ONE barrier; then 32 iters of
// {vf4 L2 load, 12 VALU, vf4 nontemporal store} per wave (1KB/instr).
// ---------------------------------------------------------------------------
__global__ __launch_bounds__(256) void k_edge(
    const float* __restrict__ ws,
    const float* __restrict__ scale, const float* __restrict__ bias,
    const float* __restrict__ r,
    float* __restrict__ out)
{
    const int bx = blockIdx.x;
    const int i  = bx & 255;
    const int br = (bx >> 8) & 1;
    const int t  = bx >> 9;
    const int tid = threadIdx.x;
    const int wave = tid >> 6, lane = tid & 63;
    const int fo = (lane & 31) * 4;   // channel offset (4 ch/lane)
    const int jh = lane >> 5;         // which row of the pair

    const float* A = ws + (2 * br) * 262144 + (t * NN + i) * FF;
    const float* B = ws + (2 * br + 1) * 262144 + t * NN * FF;

    __shared__ float r_lds[NN];

    // stage r row, zeroing the diagonal entry at stage time
    if (tid < 64) {
        const vf4* rr = (const vf4*)(r + ((size_t)(t * 2 + br) * NN + i) * NN);
        vf4 q = rr[tid];
        if ((i >> 2) == tid) q[i & 3] = 0.0f;
        ((vf4*)r_lds)[tid] = q;
    }

    const vf4 s4 = *(const vf4*)(scale + br * FF + fo);
    const vf4 b4 = *(const vf4*)(bias  + br * FF + fo);
    const vf4 a4 = *(const vf4*)(A + fo);
    vf4 c4;
    c4.x = fmaf(a4.x, s4.x, b4.x);
    c4.y = fmaf(a4.y, s4.y, b4.y);
    c4.z = fmaf(a4.z, s4.z, b4.z);
    c4.w = fmaf(a4.w, s4.w, b4.w);

    __syncthreads();

    vf4* obase = (vf4*)(out + ((size_t)(t * 2 + br) * NN + i) * (size_t)NN * FF);

    #pragma unroll 8
    for (int jj = 0; jj < 32; ++jj) {
        const int j = wave * 64 + jj * 2 + jh;
        vf4 b = *(const vf4*)(B + j * FF + fo);
        float rv = r_lds[j];
        vf4 v;
        v.x = fmaxf(fmaf(b.x, s4.x, c4.x), 0.f) * rv;
        v.y = fmaxf(fmaf(b.y, s4.y, c4.y), 0.f) * rv;
        v.z = fmaxf(fmaf(b.z, s4.z, c4.z), 0.f) * rv;
        v.w = fmaxf(fmaf(b.w, s4.w, c4.w), 0.f) * rv;
        __builtin_nontemporal_store(v, &obase[(size_t)j * 32 + (lane & 31)]);
    }
}

// ---------------------------------------------------------------------------
extern "C" void kernel_launch(void* const* d_in, const int* in_sizes, int n_in,
                              void* d_out, int out_size, void* d_ws, size_t ws_size,
                              hipStream_t stream)
{
    const float* x  = (const float*)d_in[0];   // node_feats f32 [8,256,128]
    const float* w1 = (const float*)d_in[1];   // w1 f32 [128,256]
    const float* g1 = (const float*)d_in[2];
    const float* b1 = (const float*)d_in[3];
    const float* w2 = (const float*)d_in[4];
    const float* g2 = (const float*)d_in[5];
    const float* b2 = (const float*)d_in[6];

    float* ws    = (float*)d_ws;            // A1,B1,A2,B2 + B1t,B2t
    float* sums  = ws + 1572864;            // [4][8][128]
    float* sumsq = sums + 4096;             // [4][8][128]
    float* scale = sumsq + 4096;            // [2][128]
    float* bias  = scale + 256;             // [2][128]
    float* rr    = bias + 256;              // [16][256][256]
    float* out = (float*)d_out;

    k_matmul<<<256, 128, 0, stream>>>(x, w1, w2, ws);
    k_stats <<<32, 256, 0, stream>>>(ws, sums, sumsq);
    k_scale <<<1, 256, 0, stream>>>(sums, sumsq, g1, b1, g2, b2, scale, bias);
    k_denom <<<256, 256, 0, stream>>>(ws, scale, bias, rr);
    k_edge  <<<4096, 256, 0, stream>>>(ws, scale, bias, rr, out);
}

// Round 5
// 591.012 us; speedup vs baseline: 1.0199x; 1.0199x over previous
//
#include <hip/hip_runtime.h>

// Problem: T=8, N=256, F=128. All inputs/outputs FLOAT32 (per reference).
// Decomposition: y[t,i,j,f] = A[t,i,f] + B[t,j,f],
//   A = x @ w[:, :F]^T, B = x @ w[:, F:]^T   (per branch).
// BN train-mode stats decompose onto A/B:
//   mean = (SA+SB)/(T*N),  E[y^2] = (QA+QB)/(T*N) + 2*sum_t SA_t.SB_t/(T*N^2)
//
// Measured context: dur_us includes a ~343us harness poison-fill (2GiB @
// 6.25 TB/s, plain stores). Across R0-R3, four structurally different k_edge
// variants (shuffle-reduce / strided denom / fused coalesced denom / pure
// stream) ALL land at ~200-230us for 537MB written = ~2.6 TB/s. The common
// factor is __builtin_nontemporal_store. R4 = R2 (best, 572.6us) with ONE
// change: plain stores (match the fill's 6.25 TB/s path). Predicted k_edge
// ~200 -> ~110us. (R4 bench was an infra failure; this is an identical
// resubmit to run the same single-variable experiment.)

#define TT 8
#define NN 256
#define FF 128
// rows = T*N = 2048; per-array ws region = 2048*128 = 262144 floats
// ws layout (floats):
//   A1:0  B1:262144  A2:524288  B2:786432
//   B1t:1048576  B2t:1310720          (each [8 t][128 f][256 j])
//   sums:1572864[4096] sumsq:1576960[4096] scale:1581056[256] bias:1581312[256]

typedef float vf4 __attribute__((ext_vector_type(4)));

// ---------------------------------------------------------------------------
// Kernel 1: A1,B1,A2,B2 [2048 rows][128 f] (+ transposed B1t,B2t) from x, w.
// 256 blocks x 128 threads; block = 8 rows; thread = output channel f.
// ---------------------------------------------------------------------------
__global__ __launch_bounds__(128) void k_matmul(
    const float* __restrict__ x,    // [2048][128]
    const float* __restrict__ w1,   // [128][256]
    const float* __restrict__ w2,   // [128][256]
    float* __restrict__ ws)
{
    __shared__ float xs[8][FF];
    const int tid = threadIdx.x;
    const int row0 = blockIdx.x * 8;

    {
        const float4* xv = (const float4*)(x + row0 * FF);
        ((float4*)xs)[tid]       = xv[tid];
        ((float4*)xs)[tid + 128] = xv[tid + 128];
    }
    __syncthreads();

    const int f = tid;
    float acc0[8], acc1[8], acc2[8], acc3[8];
    #pragma unroll
    for (int r = 0; r < 8; ++r) { acc0[r]=0.f; acc1[r]=0.f; acc2[r]=0.f; acc3[r]=0.f; }

    const float4* w1v = (const float4*)w1;  // row f = 64 float4 (32 A-half, 32 B-half)
    const float4* w2v = (const float4*)w2;

    #pragma unroll 4
    for (int c4 = 0; c4 < 32; ++c4) {
        float4 qa1 = w1v[f * 64 + c4];
        float4 qb1 = w1v[f * 64 + 32 + c4];
        float4 qa2 = w2v[f * 64 + c4];
        float4 qb2 = w2v[f * 64 + 32 + c4];
        const int c = c4 * 4;
        #pragma unroll
        for (int r = 0; r < 8; ++r) {
            float x0 = xs[r][c], x1 = xs[r][c + 1], x2 = xs[r][c + 2], x3 = xs[r][c + 3];
            acc0[r] = fmaf(x0, qa1.x, fmaf(x1, qa1.y, fmaf(x2, qa1.z, fmaf(x3, qa1.w, acc0[r]))));
            acc1[r] = fmaf(x0, qb1.x, fmaf(x1, qb1.y, fmaf(x2, qb1.z, fmaf(x3, qb1.w, acc1[r]))));
            acc2[r] = fmaf(x0, qa2.x, fmaf(x1, qa2.y, fmaf(x2, qa2.z, fmaf(x3, qa2.w, acc2[r]))));
            acc3[r] = fmaf(x0, qb2.x, fmaf(x1, qb2.y, fmaf(x2, qb2.z, fmaf(x3, qb2.w, acc3[r]))));
        }
    }

    float* A1 = ws;
    float* B1 = ws + 262144;
    float* A2 = ws + 524288;
    float* B2 = ws + 786432;
    #pragma unroll
    for (int r = 0; r < 8; ++r) {
        int row = row0 + r;
        A1[row * FF + f] = acc0[r];
        B1[row * FF + f] = acc1[r];
        A2[row * FF + f] = acc2[r];
        B2[row * FF + f] = acc3[r];
    }

    // transposed B copies: thread f holds B[row0..row0+7][f] in acc1/acc3
    // Bt layout per array: [t][f][256 j]; all 8 rows of a block share one t.
    {
        const int t  = row0 >> 8;
        const int n0 = row0 & 255;
        float* b1t = ws + 1048576 + (t * FF + f) * NN + n0;
        float* b2t = ws + 1310720 + (t * FF + f) * NN + n0;
        vf4 p0 = {acc1[0], acc1[1], acc1[2], acc1[3]};
        vf4 p1 = {acc1[4], acc1[5], acc1[6], acc1[7]};
        vf4 q0 = {acc3[0], acc3[1], acc3[2], acc3[3]};
        vf4 q1 = {acc3[4], acc3[5], acc3[6], acc3[7]};
        *(vf4*)(b1t)     = p0;
        *(vf4*)(b1t + 4) = p1;
        *(vf4*)(b2t)     = q0;
        *(vf4*)(b2t + 4) = q1;
    }
}

// ---------------------------------------------------------------------------
// Kernel 2a: per-(array, t) channel sums and sum-of-squares over n.
// grid = 32 (t in [0,8) x arr in [0,4)), block = 256.
// ---------------------------------------------------------------------------
__global__ __launch_bounds__(256) void k_stats(
    const float* __restrict__ ab,
    float* __restrict__ sums, float* __restrict__ sumsq)
{
    const int bx = blockIdx.x;
    const int t = bx & 7, arr = bx >> 3;
    const float* A = ab + arr * 262144 + t * NN * FF;
    const int tid = threadIdx.x;
    const int f = tid & 127, h = tid >> 7;
    float s = 0.f, q = 0.f;
    for (int n = h; n < NN; n += 2) {
        float v = A[n * FF + f];
        s += v;
        q = fmaf(v, v, q);
    }
    __shared__ float ls[256], lq[256];
    ls[tid] = s; lq[tid] = q;
    __syncthreads();
    if (tid < 128) {
        sums [(arr * 8 + t) * FF + f] = ls[tid] + ls[tid + 128];
        sumsq[(arr * 8 + t) * FF + f] = lq[tid] + lq[tid + 128];
    }
}

// ---------------------------------------------------------------------------
// Kernel 2b: fold BN (train-mode, biased var) into per-channel scale/bias.
// 1 block x 256 threads (branch = tid>>7, f = tid&127).
// ---------------------------------------------------------------------------
__global__ __launch_bounds__(256) void k_scale(
    const float* __restrict__ sums, const float* __restrict__ sumsq,
    const float* __restrict__ g1, const float* __restrict__ b1,
    const float* __restrict__ g2, const float* __restrict__ b2,
    float* __restrict__ scale, float* __restrict__ bias)
{
    const int tid = threadIdx.x;
    const int br = tid >> 7, f = tid & 127;
    const int aA = 2 * br, aB = 2 * br + 1;
    float SA = 0.f, SB = 0.f, QA = 0.f, QB = 0.f, cross = 0.f;
    #pragma unroll
    for (int t = 0; t < TT; ++t) {
        float sa = sums[(aA * 8 + t) * FF + f];
        float sb = sums[(aB * 8 + t) * FF + f];
        SA += sa; SB += sb;
        cross = fmaf(sa, sb, cross);
        QA += sumsq[(aA * 8 + t) * FF + f];
        QB += sumsq[(aB * 8 + t) * FF + f];
    }
    const float invTN  = 1.0f / 2048.0f;    // 1/(T*N)
    const float invTNN = 1.0f / 262144.0f;  // 2/(T*N*N)
    float mA = SA * invTN, mB = SB * invTN;
    float m = mA + mB;
    float ey2 = (QA + QB) * invTN + cross * invTNN;
    float var = ey2 - m * m;
    float gf = br ? g2[f] : g1[f];
    float bf = br ? b2[f] : b1[f];
    float sc = gf * rsqrtf(var + 1e-5f);
    scale[br * FF + f] = sc;
    bias [br * FF + f] = bf - m * sc;
}

// ---------------------------------------------------------------------------
// Kernel 4: the streaming kernel, shuffle-free, fully coalesced.
// One block per output row-panel (t,br,i): 256 threads.
//   Phase 0: stage s[f] and c[f] = s[f]*A[i,f]+bias[f] into LDS.
//   Phase 1: L1 denominators from TRANSPOSED Bt[f][j]: thread (fq,jq) sums
//            its f-quarter for a j-quad via coalesced vf4 loads (1KB/instr),
//            then a 2-stage LDS combine -> r_lds[j] = 1/max(l1,eps).
//   Phase 2: pure stream. Wave w covers j in [64w,64w+64), 2 rows/iter;
//            16B/lane load + 16B/lane PLAIN store (1 KB contiguous).
// ---------------------------------------------------------------------------
__global__ __launch_bounds__(256) void k_edge(
    const float* __restrict__ ws,
    const float* __restrict__ scale, const float* __restrict__ bias,
    float* __restrict__ out)
{
    const int bx = blockIdx.x;
    const int i  = bx & 255;
    const int br = (bx >> 8) & 1;
    const int t  = bx >> 9;
    const int tid = threadIdx.x;

    const float* A  = ws + (2 * br) * 262144 + (t * NN + i) * FF;
    const float* B  = ws + (2 * br + 1) * 262144 + t * NN * FF;
    const float* Bt = ws + 1048576 + br * 262144 + t * FF * NN;  // [128 f][256 j]

    __shared__ float sc_lds[FF];
    __shared__ float cc_lds[FF];
    __shared__ vf4   part[4][NN / 4];  // per-f-quarter partial L1 sums
    __shared__ float r_lds[NN];        // 1/l1 per row j

    // phase 0
    if (tid < FF) {
        float sf = scale[br * FF + tid];
        float cf = fmaf(A[tid], sf, bias[br * FF + tid]);
        sc_lds[tid] = sf;
        cc_lds[tid] = cf;
    }
    __syncthreads();

    // phase 1: coalesced denominator pass over Bt
    {
        const int jq = tid & 63;    // j-quad: j = 4*jq .. 4*jq+3
        const int fq = tid >> 6;    // f-quarter: f = 32*fq .. 32*fq+31
        const float* bt = Bt + (fq * 32) * NN + jq * 4;
        float s0 = 0.f, s1 = 0.f, s2 = 0.f, s3 = 0.f;
        #pragma unroll 8
        for (int ff = 0; ff < 32; ++ff) {
            vf4 b = *(const vf4*)(bt + ff * NN);
            const int f = fq * 32 + ff;
            float sf = sc_lds[f];   // wave-uniform -> LDS broadcast
            float cf = cc_lds[f];
            s0 += fmaxf(fmaf(b.x, sf, cf), 0.f);
            s1 += fmaxf(fmaf(b.y, sf, cf), 0.f);
            s2 += fmaxf(fmaf(b.z, sf, cf), 0.f);
            s3 += fmaxf(fmaf(b.w, sf, cf), 0.f);
        }
        vf4 p = {s0, s1, s2, s3};
        part[fq][jq] = p;
    }
    __syncthreads();
    {
        // combine the 4 f-quarter partials for row j = tid
        const float* p0 = (const float*)&part[0][0];
        const float* p1 = (const float*)&part[1][0];
        const float* p2 = (const float*)&part[2][0];
        const float* p3 = (const float*)&part[3][0];
        float l1 = p0[tid] + p1[tid] + p2[tid] + p3[tid];
        r_lds[tid] = 1.0f / fmaxf(l1, 1e-12f);
    }
    __syncthreads();

    // phase 2: pure stream
    const int wave = tid >> 6, lane = tid & 63;
    const int fo = (lane & 31) * 4;   // channel offset (4 ch/lane)
    const int jh = lane >> 5;         // which row of the pair

    const vf4 s4 = *(const vf4*)(sc_lds + fo);
    const vf4 c4 = *(const vf4*)(cc_lds + fo);

    vf4* obase = (vf4*)(out + ((size_t)(t * 2 + br) * NN + i) * (size_t)NN * FF);

    #pragma unroll 4
    for (int jj = 0; jj < 32; ++jj) {
        const int j = wave * 64 + jj * 2 + jh;
        vf4 b = *(const vf4*)(B + j * FF + fo);
        float r = r_lds[j];
        r = (j == i) ? 0.0f : r;   // zeroed diagonal folds into r
        vf4 v;
        v.x = fmaxf(fmaf(b.x, s4.x, c4.x), 0.f) * r;
        v.y = fmaxf(fmaf(b.y, s4.y, c4.y), 0.f) * r;
        v.z = fmaxf(fmaf(b.z, s4.z, c4.z), 0.f) * r;
        v.w = fmaxf(fmaf(b.w, s4.w, c4.w), 0.f) * r;
        obase[(size_t)j * 32 + (lane & 31)] = v;   // PLAIN store (R4's one change)
    }
}

// ---------------------------------------------------------------------------
extern "C" void kernel_launch(void* const* d_in, const int* in_sizes, int n_in,
                              void* d_out, int out_size, void* d_ws, size_t ws_size,
                              hipStream_t stream)
{
    const float* x  = (const float*)d_in[0];   // node_feats f32 [8,256,128]
    const float* w1 = (const float*)d_in[1];   // w1 f32 [128,256]
    const float* g1 = (const float*)d_in[2];
    const float* b1 = (const float*)d_in[3];
    const float* w2 = (const float*)d_in[4];
    const float* g2 = (const float*)d_in[5];
    const float* b2 = (const float*)d_in[6];

    float* ws    = (float*)d_ws;            // A1,B1,A2,B2 + B1t,B2t
    float* sums  = ws + 1572864;            // [4][8][128]
    float* sumsq = sums + 4096;             // [4][8][128]
    float* scale = sumsq + 4096;            // [2][128]
    float* bias  = scale + 256;             // [2][128]
    float* out = (float*)d_out;

    k_matmul<<<256, 128, 0, stream>>>(x, w1, w2, ws);
    k_stats <<<32, 256, 0, stream>>>(ws, sums, sumsq);
    k_scale <<<1, 256, 0, stream>>>(sums, sumsq, g1, b1, g2, b2, scale, bias);
    k_edge  <<<4096, 256, 0, stream>>>(ws, scale, bias, out);
}